// Round 11
// baseline (329.381 us; speedup 1.0000x reference)
//
#include <hip/hip_runtime.h>
#include <hip/hip_bf16.h>

// Problem constants: B=16, N=1024, D=768 -> T=16384 tokens.
#define T_TOK   16384
#define D_DIM   768
#define ROWB    1536          // bytes per row (768 * 2B bf16)
#define INV_TEMP (1.0f/0.07f)
#define XROWS   17152
#define XALL_BYTES (XROWS * ROWB)

typedef __bf16 bf16x8 __attribute__((ext_vector_type(8)));
typedef float  f32x4  __attribute__((ext_vector_type(4)));
typedef unsigned int u32;

__device__ __forceinline__ u32 f2u(float f) {
    u32 b = __float_as_uint(f);
    return (b & 0x80000000u) ? ~b : (b | 0x80000000u);
}
__device__ __forceinline__ float u2f(u32 u) {
    u32 b = (u & 0x80000000u) ? (u & 0x7FFFFFFFu) : ~u;
    return __uint_as_float(b);
}

__device__ __forceinline__ void gload16(const void* g, void* l) {
    __builtin_amdgcn_global_load_lds((const __attribute__((address_space(1))) u32*)g,
                                     (__attribute__((address_space(3))) u32*)l,
                                     16, 0, 0);
}

// ============================================================================
// K1: class-wise prefix scan. meta[0]=R, meta[1]=F, meta[2]=Rpad(256-aligned).
// ============================================================================
__global__ void k_scan(const int* __restrict__ labels, int* __restrict__ pos,
                       int* __restrict__ meta)
{
    __shared__ int sr[256], sf[256];
    const int t = threadIdx.x;
    const int base = t * 64;
    int cr = 0, cf = 0;
    for (int i = 0; i < 64; ++i) {
        int v = labels[base + i];
        cr += (v == 0);
        cf += (v == 1);
    }
    sr[t] = cr; sf[t] = cf;
    __syncthreads();
    if (t == 0) {
        int ar = 0, af = 0;
        for (int i = 0; i < 256; ++i) {
            int r = sr[i]; sr[i] = ar; ar += r;
            int f = sf[i]; sf[i] = af; af += f;
        }
        meta[0] = ar;
        meta[1] = af;
        meta[2] = (ar + 255) & ~255;
    }
    __syncthreads();
    int pr = sr[t], pf = sf[t];
    for (int i = 0; i < 64; ++i) {
        int v = labels[base + i];
        pos[base + i] = (v == 0) ? pr++ : pf++;
    }
}

// ============================================================================
// K2: L2-normalize rows, bf16-convert, scatter compacted by class.
// ============================================================================
__global__ void k_norm(const float* __restrict__ x, const int* __restrict__ labels,
                       const int* __restrict__ pos, const int* __restrict__ meta,
                       __hip_bfloat16* __restrict__ Xall)
{
    const int row = blockIdx.x;
    const int t = threadIdx.x;
    const float* xr = x + (size_t)row * D_DIM;
    float a0 = xr[t], a1 = xr[t + 256], a2 = xr[t + 512];
    float ss = a0 * a0 + a1 * a1 + a2 * a2;
    #pragma unroll
    for (int m = 32; m >= 1; m >>= 1) ss += __shfl_xor(ss, m);
    __shared__ float sred[4];
    if ((t & 63) == 0) sred[t >> 6] = ss;
    __syncthreads();
    float tot = sred[0] + sred[1] + sred[2] + sred[3];
    float inv = 1.0f / fmaxf(sqrtf(tot), 1e-12f);
    int lab = labels[row];
    int base = (lab == 0) ? pos[row] : (meta[2] + pos[row]);
    __hip_bfloat16* dst = Xall + (size_t)base * D_DIM;
    dst[t]       = __float2bfloat16(a0 * inv);
    dst[t + 256] = __float2bfloat16(a1 * inv);
    dst[t + 512] = __float2bfloat16(a2 * inv);
}

// ============================================================================
// K3 (round 11): r10 skeleton + A DIRECT from global to registers.
//  - B: LDS double buffer (2 x 16 KiB), same verified swizzled stage/read.
//  - A: per-lane global dwordx4 loads into named double-buffered reg sets
//    (afrA/afrB); fragment content IDENTICAL to the verified LDS path:
//    row = wm*64 + mm*16 + li, bytes kt*128 + lg*16 (+64 for k=1).
//  - Sync is COUNTING-FREE (the r8/r9 counted-vmcnt failure is excluded):
//    every tile ends "s_waitcnt vmcnt(0); s_barrier" (DRAIN0) which forces
//    ALL vm ops (B stages, A loads, atomics) complete -- no FIFO-order
//    assumptions. RAW: stages forced+barrier'd before next tile's reads.
//    WAR: tile reads consumed (lgkm) before barrier arrival; next write to
//    that buffer issues after the barrier.
//  - LDS/block 32 KiB, traffic/block-tile 48 KiB (was 96) -> LDS floor ~30us;
//    VGPR ~110-120 -> 3-4 blocks/CU (Gm=16, P=1024 blocks = 4/CU).
// ============================================================================
#define MFMA16(a,b,c) __builtin_amdgcn_mfma_f32_16x16x32_bf16(a,b,c,0,0,0)
#define LB_(b) (lds + (b)*16384)

// step s -> (bi=s/12, kt=s%12); wave-uniform scalar math.
#define STAGE_B(b,s) do { \
    int bi_ = (s)/12, kt_ = (s)%12; \
    const char* bp_ = Bb + (size_t)(grp + Gm*bi_) * (128*ROWB) + boff + kt_*128; \
    gload16(bp_,           LB_(b) + wq); \
    gload16(bp_ +  49152,  LB_(b) + wq + 4096); \
    gload16(bp_ +  98304,  LB_(b) + wq + 8192); \
    gload16(bp_ + 147456,  LB_(b) + wq + 12288); } while(0)

// A fragments direct from global (L2-resident panel), named dest reg set.
#define ALOAD(dst,s) do { \
    int kt_ = (s)%12; \
    const char* ap_ = Ab + arowB + kt_*128 + lgo; \
    dst[0][0] = *(const bf16x8*)(ap_); \
    dst[0][1] = *(const bf16x8*)(ap_ + 64); \
    dst[1][0] = *(const bf16x8*)(ap_ + 16*ROWB); \
    dst[1][1] = *(const bf16x8*)(ap_ + 16*ROWB + 64); \
    dst[2][0] = *(const bf16x8*)(ap_ + 32*ROWB); \
    dst[2][1] = *(const bf16x8*)(ap_ + 32*ROWB + 64); \
    dst[3][0] = *(const bf16x8*)(ap_ + 48*ROWB); \
    dst[3][1] = *(const bf16x8*)(ap_ + 48*ROWB + 64); } while(0)

#define DRAIN0 asm volatile("s_waitcnt vmcnt(0)\n\ts_barrier" ::: "memory")

#define LOAD_B0(b) do { \
    _Pragma("unroll") \
    for (int nn = 0; nn < 2; ++nn) { \
        bfrA[nn][0] = *(const bf16x8*)(LB_(b) + bBase + nn*2048 + cb0); \
        bfrA[nn][1] = *(const bf16x8*)(LB_(b) + bBase + nn*2048 + cb1); } } while(0)
#define LOAD_B1(b) do { \
    _Pragma("unroll") \
    for (int nn = 0; nn < 2; ++nn) { \
        bfrB[nn][0] = *(const bf16x8*)(LB_(b) + bBase + (2+nn)*2048 + cb0); \
        bfrB[nn][1] = *(const bf16x8*)(LB_(b) + bBase + (2+nn)*2048 + cb1); } } while(0)

#define MM(nbase,A,bvx) do { \
    __builtin_amdgcn_s_setprio(1); \
    _Pragma("unroll") \
    for (int mm = 0; mm < 4; ++mm) { \
        _Pragma("unroll") \
        for (int nn = 0; nn < 2; ++nn) { \
            acc[mm][(nbase)+nn] = MFMA16(A[mm][0], bvx[nn][0], acc[mm][(nbase)+nn]); \
            acc[mm][(nbase)+nn] = MFMA16(A[mm][1], bvx[nn][1], acc[mm][(nbase)+nn]); } } \
    __builtin_amdgcn_s_setprio(0); \
} while(0)

#define TILE(b,CUR,NXT,t) do { \
    int s_ = (t)+1; if (s_ > NS-1) s_ = NS-1; \
    STAGE_B((b)^1, s_); \
    ALOAD(NXT, s_); \
    LOAD_B0(b); \
    MM(0, CUR, bfrA); \
    LOAD_B1(b); \
    MM(2, CUR, bfrB); \
    DRAIN0; \
} while(0)

__global__ __launch_bounds__(256, 3) void k_gemm(const __hip_bfloat16* __restrict__ Xall,
                                                 const int* __restrict__ meta,
                                                 u32* __restrict__ rowmax,
                                                 u32* __restrict__ colmax)
{
    const int R = meta[0], Fc = meta[1], Rpad = meta[2];
    const int nbm = (R + 127) >> 7;
    const int nbn = (Fc + 127) >> 7;
    if (nbm == 0 || nbn == 0) return;
    const int Gm = (nbn < 16) ? nbn : 16;
    const int P  = nbm * Gm;

    __shared__ __align__(16) char lds[32768];

    const int tid = threadIdx.x;
    const int w  = tid >> 6, l = tid & 63;
    const int wm = w >> 1, wn = w & 1;
    const int lg = l >> 4, li = l & 15;
    const int wq = w * 1024;

    // B staging geometry (verified): thread covers rows srow+{0,32,64,96},
    // pre-swizzled source chunk (tid&7)^(row&7) -> linear LDS dest.
    const int srow = tid >> 3;
    const int ch   = ((tid & 7) ^ (srow & 7)) * 16;
    const int boff = srow * ROWB + ch;

    const char* Bb = (const char*)Xall + (size_t)Rpad * ROWB;

    // MFMA read geometry
    const int arowB = (wm * 64 + li) * ROWB;  // A direct: per-lane row base
    const int lgo   = lg * 16;
    const int bBase = (wn * 64 + li) * 128;   // B from LDS (swizzled)
    const int sw  = li & 7;
    const int cb0 = (lg ^ sw) * 16;
    const int cb1 = ((4 + lg) ^ sw) * 16;

    const float MASKED = -3.0f;
    f32x4 acc[4][4];
    #pragma unroll
    for (int m = 0; m < 4; ++m)
        #pragma unroll
        for (int n = 0; n < 4; ++n)
            acc[m][n] = (f32x4){0.f, 0.f, 0.f, 0.f};

    bf16x8 afrA[4][2], afrB[4][2], bfrA[2][2], bfrB[2][2];

    #pragma unroll 1
    for (int p = blockIdx.x; p < P; p += (int)gridDim.x) {
        // ---- decode (bm, grp); XCD-clustered in the common case ----
        int bm, grp;
        if (nbm == 64 && Gm == 16) {
            int xcd = p & 7, i = p >> 3;
            bm = ((i & 7) << 3) + xcd;   // XCD x owns bm == x (mod 8)
            grp = i >> 3;                // [0,16)
        } else {
            bm = p % nbm; grp = p / nbm;
        }
        const int nt = (nbn - grp + Gm - 1) / Gm;
        const int NS = 12 * nt;

        const char* Ab = (const char*)Xall + (size_t)(bm * 128) * ROWB;

        // prologue: B(0) -> buf0, A(0) -> afrA; drain (counting-free)
        STAGE_B(0, 0);
        ALOAD(afrA, 0);
        DRAIN0;

        #pragma unroll 1
        for (int th = 0; th < NS; th += 2) {
            TILE(0, afrA, afrB, th);
            TILE(1, afrB, afrA, th + 1);

            if (((th + 1) % 12) == 11) {
                // ---- per-bn register epilogue (no barriers) ----
                const int bnv = grp + Gm * ((th + 1) / 12);
                #pragma unroll
                for (int m = 0; m < 4; ++m)
                    #pragma unroll
                    for (int reg = 0; reg < 4; ++reg) {
                        float v = MASKED;
                        #pragma unroll
                        for (int n = 0; n < 4; ++n) {
                            int gc = bnv * 128 + wn * 64 + n * 16 + li;
                            v = fmaxf(v, (gc < Fc) ? acc[m][n][reg] : MASKED);
                        }
                        v = fmaxf(v, __shfl_xor(v, 1));
                        v = fmaxf(v, __shfl_xor(v, 2));
                        v = fmaxf(v, __shfl_xor(v, 4));
                        v = fmaxf(v, __shfl_xor(v, 8));
                        int gr = bm * 128 + wm * 64 + m * 16 + lg * 4 + reg;
                        if (li == 0 && gr < R) atomicMax(&rowmax[gr], f2u(v));
                    }
                #pragma unroll
                for (int n = 0; n < 4; ++n) {
                    float v = MASKED;
                    #pragma unroll
                    for (int m = 0; m < 4; ++m)
                        #pragma unroll
                        for (int reg = 0; reg < 4; ++reg) {
                            int gr = bm * 128 + wm * 64 + m * 16 + lg * 4 + reg;
                            v = fmaxf(v, (gr < R) ? acc[m][n][reg] : MASKED);
                        }
                    v = fmaxf(v, __shfl_xor(v, 16));
                    v = fmaxf(v, __shfl_xor(v, 32));
                    int gc = bnv * 128 + wn * 64 + n * 16 + li;
                    if (lg == 0 && gc < Fc) atomicMax(&colmax[gc], f2u(v));
                }
                #pragma unroll
                for (int m = 0; m < 4; ++m)
                    #pragma unroll
                    for (int n = 0; n < 4; ++n)
                        acc[m][n] = (f32x4){0.f, 0.f, 0.f, 0.f};
            }
        }
    }
}

// ============================================================================
// K4: maxes -> loss, masked means, scalar out.
// ============================================================================
__global__ void k_final(const u32* __restrict__ rowmax, const u32* __restrict__ colmax,
                        const int* __restrict__ meta, float* __restrict__ out)
{
    const int R = meta[0], Fc = meta[1];
    const int t = threadIdx.x;
    float sr = 0.f, sf = 0.f;
    for (int i = t; i < R; i += 256) {
        u32 u = rowmax[i];
        float m = (u == 0u) ? -1e9f : u2f(u) * INV_TEMP;
        float sg = 1.0f / (1.0f + expf(-m));
        sr += -logf(1.0f - sg + 1e-6f);
    }
    for (int i = t; i < Fc; i += 256) {
        u32 u = colmax[i];
        float m = (u == 0u) ? -1e9f : u2f(u) * INV_TEMP;
        float sg = 1.0f / (1.0f + expf(-m));
        sf += -logf(1.0f - sg + 1e-6f);
    }
    #pragma unroll
    for (int msk = 32; msk >= 1; msk >>= 1) {
        sr += __shfl_xor(sr, msk);
        sf += __shfl_xor(sf, msk);
    }
    __shared__ float r4[4], f4[4];
    if ((t & 63) == 0) { r4[t >> 6] = sr; f4[t >> 6] = sf; }
    __syncthreads();
    if (t == 0) {
        float a = (r4[0] + r4[1] + r4[2] + r4[3]) / (float)((R > 0) ? R : 1);
        float b = (f4[0] + f4[1] + f4[2] + f4[3]) / (float)((Fc > 0) ? Fc : 1);
        out[0] = 0.5f * (a + b);
    }
}

// ============================================================================
extern "C" void kernel_launch(void* const* d_in, const int* in_sizes, int n_in,
                              void* d_out, int out_size, void* d_ws, size_t ws_size,
                              hipStream_t stream)
{
    (void)in_sizes; (void)n_in; (void)out_size; (void)ws_size;
    const float* x    = (const float*)d_in[0];
    const int* labels = (const int*)d_in[1];
    float* out        = (float*)d_out;

    char* ws = (char*)d_ws;
    int* meta = (int*)ws;
    int* pos  = (int*)(ws + 256);
    __hip_bfloat16* Xall = (__hip_bfloat16*)(ws + 131072);
    u32* rowmax = (u32*)(ws + 131072 + XALL_BYTES);
    u32* colmax = rowmax + 16384;

    k_scan<<<1, 256, 0, stream>>>(labels, pos, meta);
    k_norm<<<T_TOK, 256, 0, stream>>>(x, labels, pos, meta, Xall);
    hipMemsetAsync(rowmax, 0, 2 * 16384 * sizeof(u32), stream);
    k_gemm<<<1024, 256, 0, stream>>>(Xall, meta, rowmax, colmax);
    k_final<<<1, 256, 0, stream>>>(rowmax, colmax, meta, out);
}

// Round 12
// 191.838 us; speedup vs baseline: 1.7170x; 1.7170x over previous
//
#include <hip/hip_runtime.h>
#include <hip/hip_bf16.h>

// Problem constants: B=16, N=1024, D=768 -> T=16384 tokens.
#define T_TOK   16384
#define D_DIM   768
#define ROWB    1536          // bytes per row (768 * 2B bf16)
#define INV_TEMP (1.0f/0.07f)
#define XROWS   17152
#define XALL_BYTES (XROWS * ROWB)

typedef __bf16 bf16x8 __attribute__((ext_vector_type(8)));
typedef float  f32x4  __attribute__((ext_vector_type(4)));
typedef unsigned int u32;
typedef unsigned short u16;

__device__ __forceinline__ u32 f2u(float f) {
    u32 b = __float_as_uint(f);
    return (b & 0x80000000u) ? ~b : (b | 0x80000000u);
}
__device__ __forceinline__ float u2f(u32 u) {
    u32 b = (u & 0x80000000u) ? (u & 0x7FFFFFFFu) : ~u;
    return __uint_as_float(b);
}
__device__ __forceinline__ u16 f2bf(float f) {
    __hip_bfloat16 h = __float2bfloat16(f);
    u16 u; __builtin_memcpy(&u, &h, 2); return u;
}

__device__ __forceinline__ void gload16(const void* g, void* l) {
    __builtin_amdgcn_global_load_lds((const __attribute__((address_space(1))) u32*)g,
                                     (__attribute__((address_space(3))) u32*)l,
                                     16, 0, 0);
}

// ============================================================================
// K1: class-wise prefix scan + zeroing of rowmax/colmax (fused memset).
// meta[0]=R, meta[1]=F, meta[2]=Rpad(256-aligned).
// ============================================================================
__global__ void k_scan(const int* __restrict__ labels, int* __restrict__ pos,
                       int* __restrict__ meta, u32* __restrict__ rowmax)
{
    __shared__ int sr[256], sf[256];
    const int t = threadIdx.x;
    // fused zero of rowmax+colmax (contiguous 32768 u32)
    for (int i = t; i < 32768; i += 256) rowmax[i] = 0u;
    const int base = t * 64;
    int cr = 0, cf = 0;
    for (int i = 0; i < 64; ++i) {
        int v = labels[base + i];
        cr += (v == 0);
        cf += (v == 1);
    }
    sr[t] = cr; sf[t] = cf;
    __syncthreads();
    if (t == 0) {
        int ar = 0, af = 0;
        for (int i = 0; i < 256; ++i) {
            int r = sr[i]; sr[i] = ar; ar += r;
            int f = sf[i]; sf[i] = af; af += f;
        }
        meta[0] = ar;
        meta[1] = af;
        meta[2] = (ar + 255) & ~255;
    }
    __syncthreads();
    int pr = sr[t], pf = sf[t];
    for (int i = 0; i < 64; ++i) {
        int v = labels[base + i];
        pos[base + i] = (v == 0) ? pr++ : pf++;
    }
}

// ============================================================================
// K2: L2-normalize rows (float4 loads), bf16 convert (ushort4 stores),
// scatter compacted by class. 256 threads/row; threads 0..191 active on data.
// ============================================================================
__global__ void k_norm(const float* __restrict__ x, const int* __restrict__ labels,
                       const int* __restrict__ pos, const int* __restrict__ meta,
                       __hip_bfloat16* __restrict__ Xall)
{
    const int row = blockIdx.x;
    const int t = threadIdx.x;
    const float4* xr = (const float4*)(x + (size_t)row * D_DIM);
    float4 v = make_float4(0.f, 0.f, 0.f, 0.f);
    float ss = 0.f;
    if (t < 192) {
        v = xr[t];
        ss = v.x * v.x + v.y * v.y + v.z * v.z + v.w * v.w;
    }
    #pragma unroll
    for (int m = 32; m >= 1; m >>= 1) ss += __shfl_xor(ss, m);
    __shared__ float sred[4];
    if ((t & 63) == 0) sred[t >> 6] = ss;
    __syncthreads();
    float tot = sred[0] + sred[1] + sred[2] + sred[3];
    float inv = 1.0f / fmaxf(sqrtf(tot), 1e-12f);
    if (t < 192) {
        int lab = labels[row];
        int base = (lab == 0) ? pos[row] : (meta[2] + pos[row]);
        ushort4 o;
        o.x = f2bf(v.x * inv); o.y = f2bf(v.y * inv);
        o.z = f2bf(v.z * inv); o.w = f2bf(v.w * inv);
        ((ushort4*)(Xall + (size_t)base * D_DIM))[t] = o;
    }
}

// ============================================================================
// K3 (round 12): 128x128 tile, 4 waves 2x2, BK=32, FOUR LDS buffers
// (4 x 16 KiB = 64 KiB -> 2 blocks/CU), 3-deep pure-gload_lds pipeline.
//   TILE(t): STAGE(buf (t+3)%4, step t+3)   // 4 gloads (2A+2B)
//            ds_read A(4 b128) + B(4 b128) from buf t%4; 16 MFMA
//            GUARD8 = "s_waitcnt vmcnt(8); s_barrier"
// Safety (in-order vmcnt counting, verified-on-HW class from r2-r7: ALL
// counted ops are gload_lds): at guard(t) the younger-than-S(t+1) ops are
// S(t+2)[4] + S(t+3)[4] (+ any epilogue atomics) >= 8, so vmcnt(8) always
// forces S(t+1) complete (over-forcing atomics/S older ops is harmless).
// WAR: buf (t+3)%4 was last read in tile t-1; reads consumed (lgkm) before
// each wave's guard(t-1) barrier arrival; stage issues after that barrier.
// Stage->use latency = 3 tile bodies >> 900-cyc HBM.
// BK=32 swizzle (re-derived): 64B rows, 4 chunks; LDS[row][c] holds source
// chunk c ^ ((row>>1)&3); read chunk = lg ^ ((li>>1)&3) -> 2 lanes/bank
// (free per m136). Stage dest linear (gload_lds), source pre-swizzled.
// ============================================================================
#define MFMA16(a,b,c) __builtin_amdgcn_mfma_f32_16x16x32_bf16(a,b,c,0,0,0)
#define LAB(b) (lds + (b)*16384)

// step s -> (bi=s/24, kt=s%24); wave-uniform scalar math.
#define STAGE(b,s) do { \
    int bi_ = (s)/24, kt_ = (s)%24; \
    const char* ap_ = Ab + soff + kt_*64; \
    gload16(ap_,            LAB(b) + wq); \
    gload16(ap_ + 64*ROWB,  LAB(b) + wq + 4096); \
    const char* bp_ = Bb + (size_t)(grp + Gm*bi_) * (128*ROWB) + soff + kt_*64; \
    gload16(bp_,            LAB(b) + 8192 + wq); \
    gload16(bp_ + 64*ROWB,  LAB(b) + 8192 + wq + 4096); } while(0)

#define GUARD8 asm volatile("s_waitcnt vmcnt(8)\n\ts_barrier" ::: "memory")
#define DRAIN0 asm volatile("s_waitcnt vmcnt(0)\n\ts_barrier" ::: "memory")

#define LOADAB(b) do { \
    _Pragma("unroll") \
    for (int mm = 0; mm < 4; ++mm) \
        afr[mm] = *(const bf16x8*)(LAB(b) + aByte + mm*1024); \
    _Pragma("unroll") \
    for (int nn = 0; nn < 4; ++nn) \
        bfr[nn] = *(const bf16x8*)(LAB(b) + 8192 + bByte + nn*1024); } while(0)

#define TILE(b,t) do { \
    int s_ = (t)+3; if (s_ > NS-1) s_ = NS-1; \
    STAGE(((b)+3)&3, s_); \
    LOADAB(b); \
    __builtin_amdgcn_s_setprio(1); \
    _Pragma("unroll") \
    for (int mm = 0; mm < 4; ++mm) \
        _Pragma("unroll") \
        for (int nn = 0; nn < 4; ++nn) \
            acc[mm][nn] = MFMA16(afr[mm], bfr[nn], acc[mm][nn]); \
    __builtin_amdgcn_s_setprio(0); \
    GUARD8; \
} while(0)

__global__ __launch_bounds__(256, 2) void k_gemm(const __hip_bfloat16* __restrict__ Xall,
                                                 const int* __restrict__ meta,
                                                 u32* __restrict__ rowmax,
                                                 u32* __restrict__ colmax)
{
    const int R = meta[0], Fc = meta[1], Rpad = meta[2];
    const int nbm = (R + 127) >> 7;
    const int nbn = (Fc + 127) >> 7;
    if (nbm == 0 || nbn == 0) return;
    const int Gm = (nbn < 8) ? nbn : 8;
    const int P  = nbm * Gm;

    __shared__ __align__(16) char lds[65536];

    const int tid = threadIdx.x;
    const int w  = tid >> 6, l = tid & 63;
    const int wm = w >> 1, wn = w & 1;
    const int lg = l >> 4, li = l & 15;
    const int wq = w * 1024;

    // staging geometry: thread covers rows srow, srow+64; 4 chunks of 16B/row;
    // pre-swizzled source chunk c ^ ((srow>>1)&3) -> linear LDS dest.
    const int srow = tid >> 2;               // 0..63
    const int c4   = tid & 3;                // chunk 0..3
    const int ch   = (c4 ^ ((srow >> 1) & 3)) * 16;
    const int soff = srow * ROWB + ch;       // + kt*64 at stage time

    const char* Bb = (const char*)Xall + (size_t)Rpad * ROWB;

    // MFMA read geometry: row = base + li, byte = row*64 + swizzled chunk.
    const int cbA   = ((lg ^ ((li >> 1) & 3))) * 16;
    const int aByte = (wm * 64 + li) * 64 + cbA;
    const int bByte = (wn * 64 + li) * 64 + cbA;

    const float MASKED = -3.0f;
    f32x4 acc[4][4];
    #pragma unroll
    for (int m = 0; m < 4; ++m)
        #pragma unroll
        for (int n = 0; n < 4; ++n)
            acc[m][n] = (f32x4){0.f, 0.f, 0.f, 0.f};

    bf16x8 afr[4], bfr[4];

    #pragma unroll 1
    for (int p = blockIdx.x; p < P; p += (int)gridDim.x) {
        // ---- decode (bm, grp); XCD-clustered in the common case ----
        int bm, grp;
        if (nbm == 64 && Gm == 8) {
            int xcd = p & 7, i = p >> 3;
            bm = ((i & 7) << 3) + xcd;   // XCD x owns bm == x (mod 8)
            grp = i >> 3;
        } else {
            bm = p % nbm; grp = p / nbm;
        }
        const int nt = (nbn - grp + Gm - 1) / Gm;
        const int NS = 24 * nt;               // BK=32 steps in this stream

        const char* Ab = (const char*)Xall + (size_t)(bm * 128) * ROWB;

        // safety vs any prior in-flight LDS writes (no-op in the 1-pass case)
        DRAIN0;

        // prologue: stage steps 0,1,2 into bufs 0,1,2; force S(0) only.
        STAGE(0, 0);
        STAGE(1, (NS > 1) ? 1 : 0);
        STAGE(2, (NS > 2) ? 2 : 0);
        GUARD8;   // 12 outstanding -> forces S(0), leaves S(1),S(2)

        #pragma unroll 1
        for (int th = 0; th < NS; th += 4) {
            TILE(0, th);
            TILE(1, th + 1);
            TILE(2, th + 2);
            TILE(3, th + 3);

            if (((th + 3) % 24) == 23) {
                // ---- per-bn register epilogue (no barriers) ----
                const int bnv = grp + Gm * ((th + 3) / 24);
                #pragma unroll
                for (int m = 0; m < 4; ++m)
                    #pragma unroll
                    for (int reg = 0; reg < 4; ++reg) {
                        float v = MASKED;
                        #pragma unroll
                        for (int n = 0; n < 4; ++n) {
                            int gc = bnv * 128 + wn * 64 + n * 16 + li;
                            v = fmaxf(v, (gc < Fc) ? acc[m][n][reg] : MASKED);
                        }
                        v = fmaxf(v, __shfl_xor(v, 1));
                        v = fmaxf(v, __shfl_xor(v, 2));
                        v = fmaxf(v, __shfl_xor(v, 4));
                        v = fmaxf(v, __shfl_xor(v, 8));
                        int gr = bm * 128 + wm * 64 + m * 16 + lg * 4 + reg;
                        if (li == 0 && gr < R) atomicMax(&rowmax[gr], f2u(v));
                    }
                #pragma unroll
                for (int n = 0; n < 4; ++n) {
                    float v = MASKED;
                    #pragma unroll
                    for (int m = 0; m < 4; ++m)
                        #pragma unroll
                        for (int reg = 0; reg < 4; ++reg) {
                            int gr = bm * 128 + wm * 64 + m * 16 + lg * 4 + reg;
                            v = fmaxf(v, (gr < R) ? acc[m][n][reg] : MASKED);
                        }
                    v = fmaxf(v, __shfl_xor(v, 16));
                    v = fmaxf(v, __shfl_xor(v, 32));
                    int gc = bnv * 128 + wn * 64 + n * 16 + li;
                    if (lg == 0 && gc < Fc) atomicMax(&colmax[gc], f2u(v));
                }
                #pragma unroll
                for (int m = 0; m < 4; ++m)
                    #pragma unroll
                    for (int n = 0; n < 4; ++n)
                        acc[m][n] = (f32x4){0.f, 0.f, 0.f, 0.f};
            }
        }
    }
}

// ============================================================================
// K4: maxes -> loss, masked means, scalar out.
// ============================================================================
__global__ void k_final(const u32* __restrict__ rowmax, const u32* __restrict__ colmax,
                        const int* __restrict__ meta, float* __restrict__ out)
{
    const int R = meta[0], Fc = meta[1];
    const int t = threadIdx.x;
    float sr = 0.f, sf = 0.f;
    for (int i = t; i < R; i += 256) {
        u32 u = rowmax[i];
        float m = (u == 0u) ? -1e9f : u2f(u) * INV_TEMP;
        float sg = 1.0f / (1.0f + expf(-m));
        sr += -logf(1.0f - sg + 1e-6f);
    }
    for (int i = t; i < Fc; i += 256) {
        u32 u = colmax[i];
        float m = (u == 0u) ? -1e9f : u2f(u) * INV_TEMP;
        float sg = 1.0f / (1.0f + expf(-m));
        sf += -logf(1.0f - sg + 1e-6f);
    }
    #pragma unroll
    for (int msk = 32; msk >= 1; msk >>= 1) {
        sr += __shfl_xor(sr, msk);
        sf += __shfl_xor(sf, msk);
    }
    __shared__ float r4[4], f4[4];
    if ((t & 63) == 0) { r4[t >> 6] = sr; f4[t >> 6] = sf; }
    __syncthreads();
    if (t == 0) {
        float a = (r4[0] + r4[1] + r4[2] + r4[3]) / (float)((R > 0) ? R : 1);
        float b = (f4[0] + f4[1] + f4[2] + f4[3]) / (float)((Fc > 0) ? Fc : 1);
        out[0] = 0.5f * (a + b);
    }
}

// ============================================================================
extern "C" void kernel_launch(void* const* d_in, const int* in_sizes, int n_in,
                              void* d_out, int out_size, void* d_ws, size_t ws_size,
                              hipStream_t stream)
{
    (void)in_sizes; (void)n_in; (void)out_size; (void)ws_size;
    const float* x    = (const float*)d_in[0];
    const int* labels = (const int*)d_in[1];
    float* out        = (float*)d_out;

    char* ws = (char*)d_ws;
    int* meta = (int*)ws;
    int* pos  = (int*)(ws + 256);
    __hip_bfloat16* Xall = (__hip_bfloat16*)(ws + 131072);
    u32* rowmax = (u32*)(ws + 131072 + XALL_BYTES);
    u32* colmax = rowmax + 16384;

    k_scan<<<1, 256, 0, stream>>>(labels, pos, meta, rowmax);
    k_norm<<<T_TOK, 256, 0, stream>>>(x, labels, pos, meta, Xall);
    k_gemm<<<512, 256, 0, stream>>>(Xall, meta, rowmax, colmax);
    k_final<<<1, 256, 0, stream>>>(rowmax, colmax, meta, out);
}